// Round 6
// baseline (152.171 us; speedup 1.0000x reference)
//
#include <hip/hip_runtime.h>
#include <hip/hip_bf16.h>

// MHA: B=8, S=1024, D=1024, H=16, DH=64.
// R6: occupancy push on R5's register-direct-P structure. 1024 blocks
// (128q/block, 32q/wave, g=2), loop-interchanged so K frags are transient
// (8 b128/wave-tb) and V frags are shared across g (16 b64/wave-tb), VGPR
// target <=128 via __launch_bounds__(256,4) -> 4 blocks/CU, 16 waves/CU.
// P stays in registers: S^T C-layout == 16x16x16 A-layout identity.

constexpr int NB = 8, NS = 1024, ND = 1024, NH = 16, NDH = 64;

typedef __bf16 bf16x8 __attribute__((ext_vector_type(8)));
typedef short bf16x4s __attribute__((ext_vector_type(4)));
typedef float f32x4 __attribute__((ext_vector_type(4)));

__device__ __forceinline__ f32x4 mfma16(bf16x8 a, bf16x8 b, f32x4 c) {
  return __builtin_amdgcn_mfma_f32_16x16x32_bf16(a, b, c, 0, 0, 0);
}

__device__ __forceinline__ f32x4 mfma16k16(bf16x4s a, bf16x4s b, f32x4 c) {
#if __has_builtin(__builtin_amdgcn_mfma_f32_16x16x16bf16_1k)
  return __builtin_amdgcn_mfma_f32_16x16x16bf16_1k(a, b, c, 0, 0, 0);
#else
  f32x4 d;
  asm("v_mfma_f32_16x16x16_bf16 %0, %1, %2, %3"
      : "=v"(d) : "v"(a), "v"(b), "v"(c));
  return d;
#endif
}

__device__ __forceinline__ float fast_exp2(float x) {
#if __has_builtin(__builtin_amdgcn_exp2f)
  return __builtin_amdgcn_exp2f(x);   // raw v_exp_f32, no range fixup
#else
  return __builtin_exp2f(x);
#endif
}

__device__ __forceinline__ bf16x8 cvt2bf8(float4 lo, float4 hi) {
  bf16x8 r;
  r[0] = (__bf16)lo.x; r[1] = (__bf16)lo.y; r[2] = (__bf16)lo.z; r[3] = (__bf16)lo.w;
  r[4] = (__bf16)hi.x; r[5] = (__bf16)hi.y; r[6] = (__bf16)hi.z; r[7] = (__bf16)hi.w;
  return r;
}

__device__ __forceinline__ void gload16(const __hip_bfloat16* g, __hip_bfloat16* l) {
  __builtin_amdgcn_global_load_lds(
      (const __attribute__((address_space(1))) void*)g,
      (__attribute__((address_space(3))) void*)l, 16, 0, 0);
}

// Pack two f32 into a u32 of bf16s (lo in low half): round-half-up + byte perm.
__device__ __forceinline__ unsigned pack_bf16(float hi, float lo) {
  unsigned uh = __builtin_bit_cast(unsigned, hi) + 0x8000u;
  unsigned ul = __builtin_bit_cast(unsigned, lo) + 0x8000u;
  return __builtin_amdgcn_perm(uh, ul, 0x07060302u);
}

// ---------------- QKV projection (unchanged from R3) ----------------
__global__ __launch_bounds__(256) void qkv_proj_kernel(
    const float* __restrict__ x,
    const float* __restrict__ Wq, const float* __restrict__ bq,
    const float* __restrict__ Wk, const float* __restrict__ bk,
    const float* __restrict__ Wv, const float* __restrict__ bv,
    __hip_bfloat16* __restrict__ Qo, __hip_bfloat16* __restrict__ Ko,
    __hip_bfloat16* __restrict__ Vt) {
  __shared__ __align__(16) __hip_bfloat16 Wlds[3][NDH][72];
  const int tid = threadIdx.x;
  const int wave = tid >> 6, lane = tid & 63;
  const int m = lane & 15, quad = lane >> 4;
  const int h = blockIdx.x & (NH - 1);
  const int sblk = blockIdx.x >> 4;

  const float* Ws[3] = {Wq + h * 4096, Wk + h * 4096, Wv + h * 4096};
#pragma unroll
  for (int mt = 0; mt < 3; mt++) {
#pragma unroll
    for (int p = 0; p < 4; p++) {
      int idx = (p * 256 + tid) * 4;
      float4 v = *(const float4*)(Ws[mt] + idx);
      __align__(8) __hip_bfloat16 t4[4] = {
          __float2bfloat16(v.x), __float2bfloat16(v.y),
          __float2bfloat16(v.z), __float2bfloat16(v.w)};
      *(uint2*)&Wlds[mt][idx >> 6][idx & 63] = *(const uint2*)t4;
    }
  }
  __syncthreads();

  float bq4[4][4], bk4[4][4], bvv[4];
#pragma unroll
  for (int nt = 0; nt < 4; nt++) {
    float4 a = *(const float4*)(bq + h * 64 + nt * 16 + quad * 4);
    float4 c = *(const float4*)(bk + h * 64 + nt * 16 + quad * 4);
    bq4[nt][0] = a.x; bq4[nt][1] = a.y; bq4[nt][2] = a.z; bq4[nt][3] = a.w;
    bk4[nt][0] = c.x; bk4[nt][1] = c.y; bk4[nt][2] = c.z; bk4[nt][3] = c.w;
    bvv[nt] = bv[h * 64 + nt * 16 + m];
  }

  const int rowbase = sblk * 256 + wave * 64;
  bf16x8 Xf[4][2];
#pragma unroll
  for (int st = 0; st < 4; st++) {
    const float* xp = x + (size_t)(rowbase + st * 16 + m) * ND + h * NDH + quad * 8;
#pragma unroll
    for (int c = 0; c < 2; c++) {
      float4 lo = *(const float4*)(xp + c * 32);
      float4 hi = *(const float4*)(xp + c * 32 + 4);
      Xf[st][c] = cvt2bf8(lo, hi);
    }
  }

  const int b = rowbase >> 10;
  const int s0 = rowbase & 1023;
  const float qscale = 0.18033688011112042f;  // log2(e)/sqrt(64)

#pragma unroll
  for (int mt = 0; mt < 3; mt++) {
#pragma unroll
    for (int nt = 0; nt < 4; nt++) {
      bf16x8 w0 = *(const bf16x8*)&Wlds[mt][nt * 16 + m][quad * 8];
      bf16x8 w1 = *(const bf16x8*)&Wlds[mt][nt * 16 + m][32 + quad * 8];
#pragma unroll
      for (int st = 0; st < 4; st++) {
        f32x4 acc = {0.f, 0.f, 0.f, 0.f};
        if (mt < 2) {
          acc = mfma16(w0, Xf[st][0], acc);
          acc = mfma16(w1, Xf[st][1], acc);
          const int srow = s0 + st * 16 + m;
          __align__(8) __hip_bfloat16 t4[4];
          if (mt == 0) {
#pragma unroll
            for (int r = 0; r < 4; r++)
              t4[r] = __float2bfloat16((acc[r] + bq4[nt][r]) * qscale);
            *(uint2*)(Qo + ((size_t)(b * NH + h) * NS + srow) * NDH +
                      nt * 16 + quad * 4) = *(const uint2*)t4;
          } else {
#pragma unroll
            for (int r = 0; r < 4; r++)
              t4[r] = __float2bfloat16(acc[r] + bk4[nt][r]);
            *(uint2*)(Ko + ((size_t)(b * NH + h) * NS + srow) * NDH +
                      nt * 16 + quad * 4) = *(const uint2*)t4;
          }
        } else {
          acc = mfma16(Xf[st][0], w0, acc);
          acc = mfma16(Xf[st][1], w1, acc);
          __align__(8) __hip_bfloat16 t4[4];
#pragma unroll
          for (int r = 0; r < 4; r++) t4[r] = __float2bfloat16(acc[r] + bvv[nt]);
          *(uint2*)(Vt + ((size_t)(b * NH + h) * NDH + nt * 16 + m) * NS + s0 +
                    st * 16 + quad * 4) = *(const uint2*)t4;
        }
      }
    }
  }
}

// ---------------- Attention ----------------
__global__ __launch_bounds__(256, 4) void attn_kernel(
    const __hip_bfloat16* __restrict__ Q,   // [B,H,S,DH] pre-scaled
    const __hip_bfloat16* __restrict__ K,   // [B,H,S,DH]
    const __hip_bfloat16* __restrict__ Vt,  // [B,H,DH,S]
    float* __restrict__ out) {              // [B,S,D]
  // Unpadded (global_load_lds), XOR-swizzled at 16B granularity. 32 KB total.
  __shared__ __align__(16) __hip_bfloat16 Kt[2][64][64];
  __shared__ __align__(16) __hip_bfloat16 Vl[2][64][64];

  const int tid = threadIdx.x;
  const int wave = tid >> 6, lane = tid & 63;
  const int m = lane & 15, quad = lane >> 4;

  // 1024 blocks: XCD swizzle keeps one bh's qblk-siblings on one XCD.
  const int xcd = blockIdx.x & 7;
  const int j = blockIdx.x >> 3;          // 0..127
  const int bh = xcd * 16 + (j & 15);
  const int qblk = j >> 4;                // 0..7
  const int qbase = qblk * 128 + wave * 32;  // 32 q-rows per wave (2 g of 16)

  const __hip_bfloat16* Qp = Q + (size_t)bh * NS * NDH;
  const __hip_bfloat16* Kp = K + (size_t)bh * NS * NDH;
  const __hip_bfloat16* Vp = Vt + (size_t)bh * NDH * NS;

  // Q as B-fragments (16x16x32): lane holds Q[q=m][d=c*32+quad*8+j']
  bf16x8 Bq[2][2];
#pragma unroll
  for (int g = 0; g < 2; g++)
#pragma unroll
    for (int c = 0; c < 2; c++)
      Bq[g][c] = *(const bf16x8*)(Qp + (size_t)(qbase + g * 16 + m) * NDH +
                                  c * 32 + quad * 8);

  f32x4 accO[2][4];
  f32x4 lsum[2];
#pragma unroll
  for (int g = 0; g < 2; g++) {
    lsum[g] = (f32x4){0.f, 0.f, 0.f, 0.f};
#pragma unroll
    for (int nt = 0; nt < 4; nt++) accO[g][nt] = (f32x4){0.f, 0.f, 0.f, 0.f};
  }
  const bf16x4s ones4 = {0x3F80, 0x3F80, 0x3F80, 0x3F80};  // bf16 1.0 x4

  const int r8 = lane >> 3;
  const int cs = (lane & 7) ^ r8;   // swizzled 16B chunk for staging
  const int pc = quad ^ (m & 7);    // physical chunk for K b128 frag reads
  // V b64 frag offsets: slab s needs t = s*16 + quad*4 + j -> 16B chunk
  // c16 = 2s|(quad>>1), phys = c16^(m&7), elem = phys*8 + (quad&1)*4.
  int voffs[4];
#pragma unroll
  for (int s = 0; s < 4; s++)
    voffs[s] = (((2 * s) | (quad >> 1)) ^ (m & 7)) * 8 + (quad & 1) * 4;

#define STAGE(buf, tb)                                                        \
  {                                                                           \
    _Pragma("unroll") for (int p = 0; p < 2; p++) {                           \
      const int row = wave * 16 + p * 8;                                      \
      gload16(Kp + (size_t)((tb) * 64 + row + r8) * NDH + cs * 8,             \
              &Kt[buf][row][0]);                                              \
      gload16(Vp + (size_t)(row + r8) * NS + (tb) * 64 + cs * 8,              \
              &Vl[buf][row][0]);                                              \
    }                                                                         \
  }

  STAGE(0, 0);

  for (int tb = 0; tb < NS / 64; tb++) {
    const int cur = tb & 1;
    __syncthreads();  // own staging drained (vmcnt 0) + block synced
    if (tb + 1 < NS / 64) STAGE(cur ^ 1, tb + 1);  // prefetch overlaps compute

    // ---- scores + exp, per t-slab: K frags transient (8 b128 total) ----
    bf16x4s Pa[2][4];  // P A-frags: [g][s], lane holds P[q=m][t=s*16+quad*4+j]
#pragma unroll
    for (int s = 0; s < 4; s++) {
      bf16x8 k0 = *(const bf16x8*)&Kt[cur][s * 16 + m][pc * 8];
      bf16x8 k1 = *(const bf16x8*)&Kt[cur][s * 16 + m][(pc ^ 4) * 8];
#pragma unroll
      for (int g = 0; g < 2; g++) {
        f32x4 a = {0.f, 0.f, 0.f, 0.f};
        a = mfma16(k0, Bq[g][0], a);
        a = mfma16(k1, Bq[g][1], a);
        uint2 w;
        w.x = pack_bf16(fast_exp2(a[1]), fast_exp2(a[0]));
        w.y = pack_bf16(fast_exp2(a[3]), fast_exp2(a[2]));
        Pa[g][s] = __builtin_bit_cast(bf16x4s, w);
      }
    }
    // ---- denominator via ones-MFMA (C rows match accO rows) ----
#pragma unroll
    for (int g = 0; g < 2; g++)
#pragma unroll
      for (int s = 0; s < 4; s++) lsum[g] = mfma16k16(Pa[g][s], ones4, lsum[g]);
    // ---- PV: V frags shared across g (16 b64 total) ----
#pragma unroll
    for (int nt = 0; nt < 4; nt++) {
      bf16x4s vf[4];
#pragma unroll
      for (int s = 0; s < 4; s++)
        vf[s] = __builtin_bit_cast(
            bf16x4s, *(const uint2*)&Vl[cur][nt * 16 + m][voffs[s]]);
#pragma unroll
      for (int g = 0; g < 2; g++)
#pragma unroll
        for (int s = 0; s < 4; s++)
          accO[g][nt] = mfma16k16(Pa[g][s], vf[s], accO[g][nt]);
    }
  }
#undef STAGE

  // ---- epilogue: O[q][e]/l[q]; q = quad*4+r, e = nt*16+m ----
  const int b = bh >> 4, h = bh & (NH - 1);
#pragma unroll
  for (int g = 0; g < 2; g++) {
#pragma unroll
    for (int r = 0; r < 4; r++) {
      float inv = 1.0f / lsum[g][r];
      int srow = qbase + g * 16 + quad * 4 + r;
      float* op = out + (size_t)(b * NS + srow) * ND + h * NDH;
#pragma unroll
      for (int nt = 0; nt < 4; nt++) op[nt * 16 + m] = accO[g][nt][r] * inv;
    }
  }
}

extern "C" void kernel_launch(void* const* d_in, const int* in_sizes, int n_in,
                              void* d_out, int out_size, void* d_ws, size_t ws_size,
                              hipStream_t stream) {
  const float* x  = (const float*)d_in[0];
  const float* Wq = (const float*)d_in[1];
  const float* bq = (const float*)d_in[2];
  const float* Wk = (const float*)d_in[3];
  const float* bk = (const float*)d_in[4];
  const float* Wv = (const float*)d_in[5];
  const float* bv = (const float*)d_in[6];
  float* out = (float*)d_out;

  const size_t elems = (size_t)NB * NH * NS * NDH;
  __hip_bfloat16* Qw = (__hip_bfloat16*)d_ws;
  __hip_bfloat16* Kw = Qw + elems;
  __hip_bfloat16* Vw = Kw + elems;

  qkv_proj_kernel<<<512, 256, 0, stream>>>(x, Wq, bq, Wk, bk, Wv, bv, Qw, Kw, Vw);
  // 128 (b,h) x 8 q-blocks of 128 rows, XCD-swizzled
  attn_kernel<<<1024, 256, 0, stream>>>(Qw, Kw, Vw, out);
}

// Round 7
// 145.654 us; speedup vs baseline: 1.0447x; 1.0447x over previous
//
#include <hip/hip_runtime.h>
#include <hip/hip_bf16.h>

// MHA: B=8, S=1024, D=1024, H=16, DH=64.
// R7: all-k32 attention. Phase-split QK^T: two 16x16x32 MFMAs per 32-t chunk
// over PERMUTED K-row sets (tile-row m <-> t = 32c + 8(m>>2) + 4p + (m&3)),
// so exp'd scores land exactly in the k32 A-fragment layout (lane q,quad
// holds t = 8*quad + 0..7). PV and ones-denominator then run at K=32.
// K tile uses swizzle f_K=(row&3)|((row&8)>>1); V reads become b128 —
// both conflict-free. g=4 (64 q/wave), 512 blocks.

constexpr int NB = 8, NS = 1024, ND = 1024, NH = 16, NDH = 64;

typedef __bf16 bf16x8 __attribute__((ext_vector_type(8)));
typedef float f32x4 __attribute__((ext_vector_type(4)));

__device__ __forceinline__ f32x4 mfma16(bf16x8 a, bf16x8 b, f32x4 c) {
  return __builtin_amdgcn_mfma_f32_16x16x32_bf16(a, b, c, 0, 0, 0);
}

__device__ __forceinline__ float fast_exp2(float x) {
#if __has_builtin(__builtin_amdgcn_exp2f)
  return __builtin_amdgcn_exp2f(x);   // raw v_exp_f32
#else
  return __builtin_exp2f(x);
#endif
}

__device__ __forceinline__ bf16x8 cvt2bf8(float4 lo, float4 hi) {
  bf16x8 r;
  r[0] = (__bf16)lo.x; r[1] = (__bf16)lo.y; r[2] = (__bf16)lo.z; r[3] = (__bf16)lo.w;
  r[4] = (__bf16)hi.x; r[5] = (__bf16)hi.y; r[6] = (__bf16)hi.z; r[7] = (__bf16)hi.w;
  return r;
}

__device__ __forceinline__ void gload16(const __hip_bfloat16* g, __hip_bfloat16* l) {
  __builtin_amdgcn_global_load_lds(
      (const __attribute__((address_space(1))) void*)g,
      (__attribute__((address_space(3))) void*)l, 16, 0, 0);
}

// Pack two f32 into a u32 of bf16s (lo in low half): round-half-up + byte perm.
__device__ __forceinline__ unsigned pack_bf16(float hi, float lo) {
  unsigned uh = __builtin_bit_cast(unsigned, hi) + 0x8000u;
  unsigned ul = __builtin_bit_cast(unsigned, lo) + 0x8000u;
  return __builtin_amdgcn_perm(uh, ul, 0x07060302u);
}

// ---------------- QKV projection (unchanged from R3) ----------------
__global__ __launch_bounds__(256) void qkv_proj_kernel(
    const float* __restrict__ x,
    const float* __restrict__ Wq, const float* __restrict__ bq,
    const float* __restrict__ Wk, const float* __restrict__ bk,
    const float* __restrict__ Wv, const float* __restrict__ bv,
    __hip_bfloat16* __restrict__ Qo, __hip_bfloat16* __restrict__ Ko,
    __hip_bfloat16* __restrict__ Vt) {
  __shared__ __align__(16) __hip_bfloat16 Wlds[3][NDH][72];
  const int tid = threadIdx.x;
  const int wave = tid >> 6, lane = tid & 63;
  const int m = lane & 15, quad = lane >> 4;
  const int h = blockIdx.x & (NH - 1);
  const int sblk = blockIdx.x >> 4;

  const float* Ws[3] = {Wq + h * 4096, Wk + h * 4096, Wv + h * 4096};
#pragma unroll
  for (int mt = 0; mt < 3; mt++) {
#pragma unroll
    for (int p = 0; p < 4; p++) {
      int idx = (p * 256 + tid) * 4;
      float4 v = *(const float4*)(Ws[mt] + idx);
      __align__(8) __hip_bfloat16 t4[4] = {
          __float2bfloat16(v.x), __float2bfloat16(v.y),
          __float2bfloat16(v.z), __float2bfloat16(v.w)};
      *(uint2*)&Wlds[mt][idx >> 6][idx & 63] = *(const uint2*)t4;
    }
  }
  __syncthreads();

  float bq4[4][4], bk4[4][4], bvv[4];
#pragma unroll
  for (int nt = 0; nt < 4; nt++) {
    float4 a = *(const float4*)(bq + h * 64 + nt * 16 + quad * 4);
    float4 c = *(const float4*)(bk + h * 64 + nt * 16 + quad * 4);
    bq4[nt][0] = a.x; bq4[nt][1] = a.y; bq4[nt][2] = a.z; bq4[nt][3] = a.w;
    bk4[nt][0] = c.x; bk4[nt][1] = c.y; bk4[nt][2] = c.z; bk4[nt][3] = c.w;
    bvv[nt] = bv[h * 64 + nt * 16 + m];
  }

  const int rowbase = sblk * 256 + wave * 64;
  bf16x8 Xf[4][2];
#pragma unroll
  for (int st = 0; st < 4; st++) {
    const float* xp = x + (size_t)(rowbase + st * 16 + m) * ND + h * NDH + quad * 8;
#pragma unroll
    for (int c = 0; c < 2; c++) {
      float4 lo = *(const float4*)(xp + c * 32);
      float4 hi = *(const float4*)(xp + c * 32 + 4);
      Xf[st][c] = cvt2bf8(lo, hi);
    }
  }

  const int b = rowbase >> 10;
  const int s0 = rowbase & 1023;
  const float qscale = 0.18033688011112042f;  // log2(e)/sqrt(64)

#pragma unroll
  for (int mt = 0; mt < 3; mt++) {
#pragma unroll
    for (int nt = 0; nt < 4; nt++) {
      bf16x8 w0 = *(const bf16x8*)&Wlds[mt][nt * 16 + m][quad * 8];
      bf16x8 w1 = *(const bf16x8*)&Wlds[mt][nt * 16 + m][32 + quad * 8];
#pragma unroll
      for (int st = 0; st < 4; st++) {
        f32x4 acc = {0.f, 0.f, 0.f, 0.f};
        if (mt < 2) {
          acc = mfma16(w0, Xf[st][0], acc);
          acc = mfma16(w1, Xf[st][1], acc);
          const int srow = s0 + st * 16 + m;
          __align__(8) __hip_bfloat16 t4[4];
          if (mt == 0) {
#pragma unroll
            for (int r = 0; r < 4; r++)
              t4[r] = __float2bfloat16((acc[r] + bq4[nt][r]) * qscale);
            *(uint2*)(Qo + ((size_t)(b * NH + h) * NS + srow) * NDH +
                      nt * 16 + quad * 4) = *(const uint2*)t4;
          } else {
#pragma unroll
            for (int r = 0; r < 4; r++)
              t4[r] = __float2bfloat16(acc[r] + bk4[nt][r]);
            *(uint2*)(Ko + ((size_t)(b * NH + h) * NS + srow) * NDH +
                      nt * 16 + quad * 4) = *(const uint2*)t4;
          }
        } else {
          acc = mfma16(Xf[st][0], w0, acc);
          acc = mfma16(Xf[st][1], w1, acc);
          __align__(8) __hip_bfloat16 t4[4];
#pragma unroll
          for (int r = 0; r < 4; r++) t4[r] = __float2bfloat16(acc[r] + bvv[nt]);
          *(uint2*)(Vt + ((size_t)(b * NH + h) * NDH + nt * 16 + m) * NS + s0 +
                    st * 16 + quad * 4) = *(const uint2*)t4;
        }
      }
    }
  }
}

// ---------------- Attention ----------------
__global__ __launch_bounds__(256, 2) void attn_kernel(
    const __hip_bfloat16* __restrict__ Q,   // [B,H,S,DH] pre-scaled
    const __hip_bfloat16* __restrict__ K,   // [B,H,S,DH]
    const __hip_bfloat16* __restrict__ Vt,  // [B,H,DH,S]
    float* __restrict__ out) {              // [B,S,D]
  // Unpadded (global_load_lds). K swizzle f_K=(row&3)|((row&8)>>1);
  // V swizzle f_V=row&7. 32 KB total.
  __shared__ __align__(16) __hip_bfloat16 Kt[2][64][64];
  __shared__ __align__(16) __hip_bfloat16 Vl[2][64][64];

  const int tid = threadIdx.x;
  const int wave = tid >> 6, lane = tid & 63;
  const int m = lane & 15, quad = lane >> 4;

  // 512 blocks: XCD swizzle keeps one bh's 4 qblk-siblings on one XCD.
  const int xcd = blockIdx.x & 7;
  const int j = blockIdx.x >> 3;          // 0..63
  const int bh = xcd * 16 + (j & 15);
  const int qblk = j >> 4;                // 0..3
  const int qbase = qblk * 256 + wave * 64;  // 64 q-rows per wave (4 g of 16)

  const __hip_bfloat16* Qp = Q + (size_t)bh * NS * NDH;
  const __hip_bfloat16* Kp = K + (size_t)bh * NS * NDH;
  const __hip_bfloat16* Vp = Vt + (size_t)bh * NDH * NS;

  // Q as B-fragments (k32): lane holds Q[q][d = dh*32 + quad*8 + j']
  bf16x8 Bq[4][2];
#pragma unroll
  for (int g = 0; g < 4; g++)
#pragma unroll
    for (int dh = 0; dh < 2; dh++)
      Bq[g][dh] = *(const bf16x8*)(Qp + (size_t)(qbase + g * 16 + m) * NDH +
                                   dh * 32 + quad * 8);

  f32x4 accO[4][4];
  f32x4 lsum[4];
#pragma unroll
  for (int g = 0; g < 4; g++) {
    lsum[g] = (f32x4){0.f, 0.f, 0.f, 0.f};
#pragma unroll
    for (int nt = 0; nt < 4; nt++) accO[g][nt] = (f32x4){0.f, 0.f, 0.f, 0.f};
  }
  bf16x8 ones8;
#pragma unroll
  for (int i = 0; i < 8; i++) ones8[i] = (__bf16)1.0f;

  const int r8 = lane >> 3;
  const int csV = (lane & 7) ^ r8;               // V staging logical chunk
  const int csK0 = (lane & 7) ^ (r8 & 3);        // K staging, p8=0 (^4 for p8=1)
  // Frag-read constants:
  const int krow = 8 * (m >> 2) + (m & 3);       // + c*32 + 4p at use site
  const int fK = (m & 3) ^ (((m >> 2) & 1) << 2);
  const int kc0 = ((quad ^ fK)) * 8;             // dh=0 chunk offset (elems)
  const int vc0 = ((quad ^ (m & 7))) * 8;        // c=0 chunk offset (elems)

#define STAGE(buf, tb)                                                        \
  {                                                                           \
    _Pragma("unroll") for (int p8 = 0; p8 < 2; p8++) {                        \
      const int row0 = wave * 16 + p8 * 8;                                    \
      gload16(Kp + (size_t)((tb) * 64 + row0 + r8) * NDH +                    \
                  (csK0 ^ (p8 * 4)) * 8,                                      \
              &Kt[buf][row0][0]);                                             \
      gload16(Vp + (size_t)(row0 + r8) * NS + (tb) * 64 + csV * 8,            \
              &Vl[buf][row0][0]);                                             \
    }                                                                         \
  }

  STAGE(0, 0);

  for (int tb = 0; tb < NS / 64; tb++) {
    const int cur = tb & 1;
    __syncthreads();  // own staging drained (vmcnt 0) + block synced
    if (tb + 1 < NS / 64) STAGE(cur ^ 1, tb + 1);  // prefetch overlaps compute

    // ---- phase-split QK^T + exp: P lands in k32 A-layout ----
    bf16x8 Pa[4][2];  // [g][c]: lane holds P[q = g*16+m... wait q=m][t=32c+8*quad+j]
#pragma unroll
    for (int c = 0; c < 2; c++) {
      uint2 pw[4][2];
#pragma unroll
      for (int p = 0; p < 2; p++) {
        const __hip_bfloat16* kr = &Kt[cur][c * 32 + 4 * p + krow][0];
        bf16x8 k0 = *(const bf16x8*)(kr + kc0);
        bf16x8 k1 = *(const bf16x8*)(kr + (kc0 ^ 32));
#pragma unroll
        for (int g = 0; g < 4; g++) {
          f32x4 a = {0.f, 0.f, 0.f, 0.f};
          a = mfma16(k0, Bq[g][0], a);
          a = mfma16(k1, Bq[g][1], a);
          pw[g][p].x = pack_bf16(fast_exp2(a[1]), fast_exp2(a[0]));
          pw[g][p].y = pack_bf16(fast_exp2(a[3]), fast_exp2(a[2]));
        }
      }
#pragma unroll
      for (int g = 0; g < 4; g++) {
        uint4 u = {pw[g][0].x, pw[g][0].y, pw[g][1].x, pw[g][1].y};
        Pa[g][c] = __builtin_bit_cast(bf16x8, u);
      }
    }
    // ---- denominator via ones-MFMA (k32; C rows match accO rows) ----
#pragma unroll
    for (int g = 0; g < 4; g++)
#pragma unroll
      for (int c = 0; c < 2; c++) lsum[g] = mfma16(Pa[g][c], ones8, lsum[g]);
    // ---- PV at k32: V frags are contiguous b128, shared across g ----
#pragma unroll
    for (int nt = 0; nt < 4; nt++) {
      const __hip_bfloat16* vr = &Vl[cur][nt * 16 + m][0];
      bf16x8 v0 = *(const bf16x8*)(vr + vc0);
      bf16x8 v1 = *(const bf16x8*)(vr + (vc0 ^ 32));
#pragma unroll
      for (int g = 0; g < 4; g++) {
        accO[g][nt] = mfma16(Pa[g][0], v0, accO[g][nt]);
        accO[g][nt] = mfma16(Pa[g][1], v1, accO[g][nt]);
      }
    }
  }
#undef STAGE

  // ---- epilogue: O[q][e]/l[q]; q = quad*4+r, e = nt*16+m ----
  const int b = bh >> 4, h = bh & (NH - 1);
#pragma unroll
  for (int g = 0; g < 4; g++) {
#pragma unroll
    for (int r = 0; r < 4; r++) {
      float inv = 1.0f / lsum[g][r];
      int srow = qbase + g * 16 + quad * 4 + r;
      float* op = out + (size_t)(b * NS + srow) * ND + h * NDH;
#pragma unroll
      for (int nt = 0; nt < 4; nt++) op[nt * 16 + m] = accO[g][nt][r] * inv;
    }
  }
}

extern "C" void kernel_launch(void* const* d_in, const int* in_sizes, int n_in,
                              void* d_out, int out_size, void* d_ws, size_t ws_size,
                              hipStream_t stream) {
  const float* x  = (const float*)d_in[0];
  const float* Wq = (const float*)d_in[1];
  const float* bq = (const float*)d_in[2];
  const float* Wk = (const float*)d_in[3];
  const float* bk = (const float*)d_in[4];
  const float* Wv = (const float*)d_in[5];
  const float* bv = (const float*)d_in[6];
  float* out = (float*)d_out;

  const size_t elems = (size_t)NB * NH * NS * NDH;
  __hip_bfloat16* Qw = (__hip_bfloat16*)d_ws;
  __hip_bfloat16* Kw = Qw + elems;
  __hip_bfloat16* Vw = Kw + elems;

  qkv_proj_kernel<<<512, 256, 0, stream>>>(x, Wq, bq, Wk, bk, Wv, bv, Qw, Kw, Vw);
  // 128 (b,h) x 4 q-blocks of 256 rows, XCD-swizzled
  attn_kernel<<<512, 256, 0, stream>>>(Qw, Kw, Vw, out);
}